// Round 9
// baseline (399.795 us; speedup 1.0000x reference)
//
#include <hip/hip_runtime.h>
#include <hip/hip_fp16.h>

#define DD 300
#define KK 50
#define BB 32
#define SS 8192
#define NN 128
#define LL 64
#define NSEG (BB * NN)   // 4096
#define NW 5             // waves per block
#define NT 320           // threads per block
#define NJ 13            // rows per wave = ceil(64/5)
#define GY 4             // segments per k_yu block
#define GR 4             // segments per k_rest block
#define RSU 152          // e16 row stride in u32 (8B-aligned rows for uint2 stores)

__device__ __forceinline__ float wave_sum(float v) {
    #pragma unroll
    for (int m = 32; m; m >>= 1) v += __shfl_xor(v, m, 64);
    return v;
}
__device__ __forceinline__ float wave_max(float v) {
    #pragma unroll
    for (int m = 32; m; m >>= 1) v = fmaxf(v, __shfl_xor(v, m, 64));
    return v;
}
__device__ __forceinline__ unsigned int pack_h2(float a, float b) {
    __half2 h = __floats2half2_rn(a, b);
    return *reinterpret_cast<const unsigned int*>(&h);
}
__device__ __forceinline__ float2 unpack_h2(unsigned int v) {
    __half2 h = *reinterpret_cast<const __half2*>(&v);
    return __half22float2(h);
}

// Issue one segment's 26 branch-free float4 row-loads into A/B registers.
// sched_barrier(0) pins the loads at the issue point (no sinking to use).
__device__ __forceinline__ void issue_rows(const float* __restrict__ emb,
    int tok, int len, int wave, int lane, float4* A, float4* B)
{
    #pragma unroll
    for (int j = 0; j < NJ; ++j) {
        const int l  = wave + j * NW;
        const int lc = (l < len) ? l : (len - 1);
        const int t  = __shfl(tok, lc);
        const float4* row4 = (const float4*)(emb + (size_t)t * DD);
        A[j] = row4[lane];          // dims 4*lane .. 4*lane+3   (0..255)
        B[j] = row4[11 + lane];     // dims 44+4*lane ..          (44..299)
    }
    __builtin_amdgcn_sched_barrier(0);
}

// ============ K1: fused y (pipelined 4-seg gather) + u GEMM (TM=4 amortized) ============
__global__ __launch_bounds__(NT, 3) void k_yu(
    const float* __restrict__ emb,
    const float* __restrict__ M_w,        // [D,D]
    const int*   __restrict__ tokens,
    const int*   __restrict__ seg_starts,
    const int*   __restrict__ seg_lens,
    float* __restrict__ out_y,            // [NSEG, D]
    float* __restrict__ u_ws)             // [NSEG, D]
{
    __shared__ float4 part4[GY][NW][75];  // 24 KB
    __shared__ float4 y4_s[GY][75];       // 4.8 KB

    const int tid  = threadIdx.x;
    const int wave = tid >> 6;
    const int lane = tid & 63;
    const int seg0 = blockIdx.x * GY;

    int lens[GY], bases[GY];
    #pragma unroll
    for (int s = 0; s < GY; ++s) {
        const int seg = seg0 + s;
        lens[s]  = seg_lens[seg];
        bases[s] = (seg >> 7) * SS + seg_starts[seg];   // N = 128
    }

    float4 A[NJ], B[NJ];
    const int tokc = tokens[bases[0] + lane];
    issue_rows(emb, tokc, lens[0], wave, lane, A, B);

    #pragma unroll
    for (int s = 0; s < GY; ++s) {
        int tokn = 0;
        if (s + 1 < GY) tokn = tokens[bases[s + 1] + lane];
        float4 aA = make_float4(0.f, 0.f, 0.f, 0.f);
        float4 aB = make_float4(0.f, 0.f, 0.f, 0.f);
        #pragma unroll
        for (int j = 0; j < NJ; ++j) {
            const int l = wave + j * NW;
            const float m = (l < lens[s]) ? 1.f : 0.f;
            aA.x += m * A[j].x; aA.y += m * A[j].y; aA.z += m * A[j].z; aA.w += m * A[j].w;
            aB.x += m * B[j].x; aB.y += m * B[j].y; aB.z += m * B[j].z; aB.w += m * B[j].w;
        }
        if (s + 1 < GY) issue_rows(emb, tokn, lens[s + 1], wave, lane, A, B);
        part4[s][wave][lane]      = aA;
        part4[s][wave][11 + lane] = aB;   // overlap 11..63 carries identical values
    }
    __syncthreads();

    if (tid < 300) {
        const int s = tid / 75, c = tid - s * 75;
        float4 sum = make_float4(0.f, 0.f, 0.f, 0.f);
        #pragma unroll
        for (int w = 0; w < NW; ++w) {
            const float4 pv = part4[s][w][c];
            sum.x += pv.x; sum.y += pv.y; sum.z += pv.z; sum.w += pv.w;
        }
        const float inv = 1.f / (float)seg_lens[seg0 + s];  // reload: avoid runtime-idx reg array
        sum.x *= inv; sum.y *= inv; sum.z *= inv; sum.w *= inv;
        y4_s[s][c] = sum;
        ((float4*)(out_y + (size_t)(seg0 + s) * DD))[c] = sum;
    }
    __syncthreads();

    if (tid < DD) {
        float acc0 = 0.f, acc1 = 0.f, acc2 = 0.f, acc3 = 0.f;
        #pragma unroll 3
        for (int e4 = 0; e4 < 75; ++e4) {
            const float m0 = M_w[(size_t)(4 * e4 + 0) * DD + tid];
            const float m1 = M_w[(size_t)(4 * e4 + 1) * DD + tid];
            const float m2 = M_w[(size_t)(4 * e4 + 2) * DD + tid];
            const float m3 = M_w[(size_t)(4 * e4 + 3) * DD + tid];
            const float4 y0 = y4_s[0][e4];
            const float4 y1 = y4_s[1][e4];
            const float4 y2 = y4_s[2][e4];
            const float4 y3 = y4_s[3][e4];
            acc0 += m0 * y0.x + m1 * y0.y + m2 * y0.z + m3 * y0.w;
            acc1 += m0 * y1.x + m1 * y1.y + m2 * y1.z + m3 * y1.w;
            acc2 += m0 * y2.x + m1 * y2.y + m2 * y2.z + m3 * y2.w;
            acc3 += m0 * y3.x + m1 * y3.y + m2 * y3.z + m3 * y3.w;
        }
        u_ws[(size_t)(seg0 + 0) * DD + tid] = acc0;
        u_ws[(size_t)(seg0 + 1) * DD + tid] = acc1;
        u_ws[(size_t)(seg0 + 2) * DD + tid] = acc2;
        u_ws[(size_t)(seg0 + 3) * DD + tid] = acc3;
    }
}

// ============ K2: 4-seg pipelined rest — raw barriers keep prefetch vmem in flight ============
__global__ __launch_bounds__(NT, 3) void k_rest(
    const float* __restrict__ emb,
    const float* __restrict__ W_w,        // [K,D]
    const float* __restrict__ T_w,        // [D,K]
    const int*   __restrict__ tokens,
    const int*   __restrict__ seg_starts,
    const int*   __restrict__ seg_lens,
    const float* __restrict__ u_ws,       // [NSEG, D]
    float* __restrict__ out_z,
    float* __restrict__ out_p,
    float* __restrict__ out_r)
{
    __shared__ unsigned int e16[LL * RSU];   // 38.9 KB fp16 rows
    __shared__ float  a_s[LL + 1];           // scores -> alpha; a_s[64] = 0 sentinel
    __shared__ float2 zp_s[NW][152];         // per-wave z partials
    __shared__ float  z_s[304];
    __shared__ float  p_s[64];

    const int tid  = threadIdx.x;
    const int wave = tid >> 6;
    const int lane = tid & 63;
    const int seg0 = blockIdx.x * GR;

    int lens[GR], bases[GR];
    #pragma unroll
    for (int s = 0; s < GR; ++s) {
        const int seg = seg0 + s;
        lens[s]  = seg_lens[seg];
        bases[s] = (seg >> 7) * SS + seg_starts[seg];
    }
    if (tid == 0) a_s[LL] = 0.f;

    float4 A[NJ], B[NJ];
    float4 U0, U1;
    const int tokc = tokens[bases[0] + lane];
    issue_rows(emb, tokc, lens[0], wave, lane, A, B);
    {
        const float4* up = (const float4*)(u_ws + (size_t)seg0 * DD);
        U0 = up[lane];
        const float4 u1r = up[11 + lane];
        U1 = (lane >= 53) ? u1r : make_float4(0.f, 0.f, 0.f, 0.f);  // B-unique dims only
    }

    #pragma unroll
    for (int g = 0; g < GR; ++g) {
        // ---------- phase 2: esc (from f32 regs) + fp16 pack + prefetch(g+1) ----------
        int tokn = 0;
        if (g + 1 < GR) tokn = tokens[bases[g + 1] + lane];
        #pragma unroll
        for (int j = 0; j < NJ; ++j) {
            const int l = wave + j * NW;
            float dot = A[j].x * U0.x + A[j].y * U0.y + A[j].z * U0.z + A[j].w * U0.w
                      + B[j].x * U1.x + B[j].y * U1.y + B[j].z * U1.z + B[j].w * U1.w;
            dot = wave_sum(dot);
            if (lane == 0 && l < lens[g]) a_s[l] = dot;
            if (l < LL) {               // wave-uniform; rows 0..63 all covered
                unsigned int* rw = &e16[l * RSU];
                *(uint2*)&rw[2 * lane]      = make_uint2(pack_h2(A[j].x, A[j].y), pack_h2(A[j].z, A[j].w));
                *(uint2*)&rw[22 + 2 * lane] = make_uint2(pack_h2(B[j].x, B[j].y), pack_h2(B[j].z, B[j].w));
            }
        }
        if (g + 1 < GR) {               // prefetch next segment: rows + u, pinned here
            issue_rows(emb, tokn, lens[g + 1], wave, lane, A, B);
            const float4* up = (const float4*)(u_ws + (size_t)(seg0 + g + 1) * DD);
            U0 = up[lane];
            const float4 u1r = up[11 + lane];
            U1 = (lane >= 53) ? u1r : make_float4(0.f, 0.f, 0.f, 0.f);
            __builtin_amdgcn_sched_barrier(0);
        }
        asm volatile("s_waitcnt lgkmcnt(0)" ::: "memory");
        __builtin_amdgcn_s_barrier();

        // ---------- phase 3: softmax over rows (wave 0) ----------
        if (wave == 0) {
            const float v  = (lane < lens[g]) ? a_s[lane] : -INFINITY;
            const float mx = wave_max(v);
            const float e  = (lane < lens[g]) ? __expf(v - mx) : 0.f;
            const float sm = wave_sum(e);
            a_s[lane] = e / sm;          // zeros for padded lanes
        }
        asm volatile("s_waitcnt lgkmcnt(0)" ::: "memory");
        __builtin_amdgcn_s_barrier();

        // ---------- phase 4: z partials from fp16 LDS ----------
        {
            float2 zA = make_float2(0.f, 0.f), zB = make_float2(0.f, 0.f), zC = make_float2(0.f, 0.f);
            #pragma unroll
            for (int j = 0; j < NJ; ++j) {
                const int l  = wave + j * NW;
                const int lr = (l < LL) ? l : (LL - 1);
                const float a = a_s[l];               // a_s[64] = 0 sentinel
                const unsigned int* ru = &e16[lr * RSU];
                const float2 fA = unpack_h2(ru[lane]);
                const float2 fB = unpack_h2(ru[64 + lane]);
                zA.x += a * fA.x; zA.y += a * fA.y;
                zB.x += a * fB.x; zB.y += a * fB.y;
                if (lane < 22) {
                    const float2 fC = unpack_h2(ru[128 + lane]);
                    zC.x += a * fC.x; zC.y += a * fC.y;
                }
            }
            zp_s[wave][lane]      = zA;
            zp_s[wave][64 + lane] = zB;
            if (lane < 22) zp_s[wave][128 + lane] = zC;
        }
        asm volatile("s_waitcnt lgkmcnt(0)" ::: "memory");
        __builtin_amdgcn_s_barrier();

        // ---------- phase 5: combine z ----------
        if (tid < 150) {
            float2 s = make_float2(0.f, 0.f);
            #pragma unroll
            for (int w = 0; w < NW; ++w) { const float2 pv = zp_s[w][tid]; s.x += pv.x; s.y += pv.y; }
            z_s[2 * tid]     = s.x;
            z_s[2 * tid + 1] = s.y;
            ((float2*)(out_z + (size_t)(seg0 + g) * DD))[tid] = s;
        }
        asm volatile("s_waitcnt lgkmcnt(0)" ::: "memory");
        __builtin_amdgcn_s_barrier();

        // ---------- phase 6: topic scores (wave-per-k) ----------
        for (int k = wave; k < KK; k += NW) {
            const float* wr = W_w + (size_t)k * DD;
            float d0 = wr[lane] * z_s[lane] + wr[lane + 64] * z_s[lane + 64]
                     + wr[lane + 128] * z_s[lane + 128] + wr[lane + 192] * z_s[lane + 192];
            if (lane < 44) d0 += wr[lane + 256] * z_s[lane + 256];
            d0 = wave_sum(d0);
            if (lane == 0) p_s[k] = d0;
        }
        asm volatile("s_waitcnt lgkmcnt(0)" ::: "memory");
        __builtin_amdgcn_s_barrier();

        // ---------- phase 7: softmax over k, write p ----------
        if (wave == 0) {
            const float v  = (lane < KK) ? p_s[lane] : -INFINITY;
            const float mx = wave_max(v);
            const float e  = (lane < KK) ? __expf(v - mx) : 0.f;
            const float sm = wave_sum(e);
            if (lane < KK) {
                const float p = e / sm;
                p_s[lane] = p;
                out_p[(size_t)(seg0 + g) * KK + lane] = p;
            }
        }
        asm volatile("s_waitcnt lgkmcnt(0)" ::: "memory");
        __builtin_amdgcn_s_barrier();

        // ---------- phase 8: r ----------
        if (tid < DD) {
            const float* trow = T_w + (size_t)tid * KK;
            float acc = 0.f;
            #pragma unroll
            for (int k = 0; k < KK; ++k) acc += p_s[k] * trow[k];
            out_r[(size_t)(seg0 + g) * DD + tid] = acc;
        }
        __builtin_amdgcn_s_barrier();   // protect e16/a_s for next seg's phase 2
    }
}

extern "C" void kernel_launch(void* const* d_in, const int* in_sizes, int n_in,
                              void* d_out, int out_size, void* d_ws, size_t ws_size,
                              hipStream_t stream) {
    const float* emb        = (const float*)d_in[0];
    const float* M_w        = (const float*)d_in[1];
    const float* W_w        = (const float*)d_in[2];
    const float* T_w        = (const float*)d_in[3];
    const int*   tokens     = (const int*)d_in[4];
    const int*   seg_starts = (const int*)d_in[5];
    const int*   seg_lens   = (const int*)d_in[6];

    float* out   = (float*)d_out;
    float* out_y = out;                                    // [NSEG*D]
    float* out_z = out + (size_t)NSEG * DD;                // [NSEG*D]
    float* out_p = out + (size_t)2 * NSEG * DD;            // [NSEG*K]
    float* out_r = out + (size_t)2 * NSEG * DD + (size_t)NSEG * KK;

    float* u_ws = (float*)d_ws;                            // [NSEG*D] = 4.9 MB

    hipLaunchKernelGGL(k_yu, dim3(NSEG / GY), dim3(NT), 0, stream,
                       emb, M_w, tokens, seg_starts, seg_lens, out_y, u_ws);
    hipLaunchKernelGGL(k_rest, dim3(NSEG / GR), dim3(NT), 0, stream,
                       emb, W_w, T_w, tokens, seg_starts, seg_lens,
                       u_ws, out_z, out_p, out_r);
}

// Round 10
// 212.651 us; speedup vs baseline: 1.8801x; 1.8801x over previous
//
#include <hip/hip_runtime.h>

#define DD 300
#define KK 50
#define BB 32
#define SS 8192
#define NN 128
#define LL 64
#define NSEG (BB * NN)   // 4096
#define TM 8             // segments per k_u block
#define NTU 320
#define TTP 304          // Tt row pitch (floats), 16B aligned
#define TTR 64           // Tt padded rows (50 real + zeros)

__device__ __forceinline__ float wave_sum(float v) {
    #pragma unroll
    for (int m = 32; m; m >>= 1) v += __shfl_xor(v, m, 64);
    return v;
}
__device__ __forceinline__ float wave_max(float v) {
    #pragma unroll
    for (int m = 32; m; m >>= 1) v = fmaxf(v, __shfl_xor(v, m, 64));
    return v;
}
__device__ __forceinline__ float dot4(float4 a, float4 b) {
    return a.x * b.x + a.y * b.y + a.z * b.z + a.w * b.w;
}
__device__ __forceinline__ void fma4(float4& acc, float s, float4 v) {
    acc.x += s * v.x; acc.y += s * v.y; acc.z += s * v.z; acc.w += s * v.w;
}

// Load 4 emb rows (row index clamped to len-1). A = dims 4*lane..4*lane+3.
// B = dims 44+4*lane.. (only meaningful for lanes >= 53; predicated).
__device__ __forceinline__ void ld_rows(const float* __restrict__ emb, int tok, int len,
                                        int l0, int lane, bool bl, float4* A, float4* B) {
    #pragma unroll
    for (int i = 0; i < 4; ++i) {
        int lc = l0 + i; lc = (lc < len) ? lc : (len - 1);
        const int t = __shfl(tok, lc);
        const float4* r4 = (const float4*)(emb + (size_t)t * DD);
        A[i] = r4[lane];
        if (bl) B[i] = r4[11 + lane];
    }
}
// Load 4 weight rows from a [rows][DD] matrix, row index clamped to rmax.
__device__ __forceinline__ void ld_wrows(const float* __restrict__ W, int rmax, int pitch,
                                         int k0, int lane, bool bl, float4* A, float4* B) {
    #pragma unroll
    for (int i = 0; i < 4; ++i) {
        int kc = k0 + i; kc = (kc < rmax) ? kc : rmax;
        const float4* r4 = (const float4*)(W + (size_t)kc * pitch);
        A[i] = r4[lane];
        if (bl) B[i] = r4[11 + lane];
    }
}

// ============ K0: transpose T_w [300][50] -> Tt [64][304] (zero padded) ============
__global__ __launch_bounds__(TTP) void k_tt(const float* __restrict__ T_w,
                                            float* __restrict__ Tt) {
    const int k = blockIdx.x;      // 0..63
    const int d = threadIdx.x;     // 0..303
    float v = 0.f;
    if (k < KK && d < DD) v = T_w[(size_t)d * KK + k];
    Tt[(size_t)k * TTP + d] = v;
}

// ============ K1: y — wave-per-segment, zero barriers, chunk-8 pipelined gather ============
__global__ __launch_bounds__(256) void k_y1(
    const float* __restrict__ emb,
    const int*   __restrict__ tokens,
    const int*   __restrict__ seg_starts,
    const int*   __restrict__ seg_lens,
    float* __restrict__ out_y)
{
    const int wave = threadIdx.x >> 6;
    const int lane = threadIdx.x & 63;
    const int seg  = blockIdx.x * 4 + wave;
    const int len  = seg_lens[seg];
    const int base = (seg >> 7) * SS + seg_starts[seg];
    const int tok  = tokens[base + lane];
    const bool bl  = (lane >= 53);

    float4 A0[4], B0[4], A1[4], B1[4];
    #pragma unroll
    for (int i = 0; i < 4; ++i) {
        B0[i] = make_float4(0.f, 0.f, 0.f, 0.f);
        B1[i] = make_float4(0.f, 0.f, 0.f, 0.f);
    }
    float4 aA = make_float4(0.f, 0.f, 0.f, 0.f);
    float4 aB = make_float4(0.f, 0.f, 0.f, 0.f);

    const int len8 = (len + 7) & ~7;
    ld_rows(emb, tok, len, 0, lane, bl, A0, B0);
    for (int l0 = 0; l0 < len8; l0 += 8) {
        ld_rows(emb, tok, len, l0 + 4, lane, bl, A1, B1);
        #pragma unroll
        for (int i = 0; i < 4; ++i) {
            const float m = (l0 + i < len) ? 1.f : 0.f;
            fma4(aA, m, A0[i]); fma4(aB, m, B0[i]);
        }
        ld_rows(emb, tok, len, l0 + 8, lane, bl, A0, B0);
        #pragma unroll
        for (int i = 0; i < 4; ++i) {
            const float m = (l0 + 4 + i < len) ? 1.f : 0.f;
            fma4(aA, m, A1[i]); fma4(aB, m, B1[i]);
        }
    }
    const float inv = 1.f / (float)len;
    aA.x *= inv; aA.y *= inv; aA.z *= inv; aA.w *= inv;
    aB.x *= inv; aB.y *= inv; aB.z *= inv; aB.w *= inv;
    float4* yo = (float4*)(out_y + (size_t)seg * DD);
    yo[lane] = aA;
    if (bl) yo[11 + lane] = aB;
}

// ============ K2: u = y @ M_w (unchanged r8 structure) ============
__global__ __launch_bounds__(NTU) void k_u(
    const float* __restrict__ y,
    const float* __restrict__ M_w,
    float* __restrict__ u)
{
    const int tid  = threadIdx.x;
    const int row0 = blockIdx.x * TM;
    if (tid >= DD) return;

    float acc[TM];
    #pragma unroll
    for (int r = 0; r < TM; ++r) acc[r] = 0.f;

    #pragma unroll 5
    for (int e = 0; e < DD; ++e) {
        const float m = M_w[(size_t)e * DD + tid];
        #pragma unroll
        for (int r = 0; r < TM; ++r)
            acc[r] += m * y[(size_t)(row0 + r) * DD + e];
    }
    #pragma unroll
    for (int r = 0; r < TM; ++r)
        u[(size_t)(row0 + r) * DD + tid] = acc[r];
}

// ============ K3: esc/softmax/z/p/r — wave-per-segment, zero LDS, zero barriers ============
__global__ __launch_bounds__(256) void k_rest(
    const float* __restrict__ emb,
    const float* __restrict__ W_w,    // [K, D]
    const float* __restrict__ T_w,    // [D, K] (fallback path)
    const float* __restrict__ Tt,     // [TTR, TTP] transposed (preferred)
    const int    use_tt,
    const int*   __restrict__ tokens,
    const int*   __restrict__ seg_starts,
    const int*   __restrict__ seg_lens,
    const float* __restrict__ u_ws,
    float* __restrict__ out_z,
    float* __restrict__ out_p,
    float* __restrict__ out_r)
{
    const int wave = threadIdx.x >> 6;
    const int lane = threadIdx.x & 63;
    const int seg  = blockIdx.x * 4 + wave;
    const int len  = seg_lens[seg];
    const int base = (seg >> 7) * SS + seg_starts[seg];
    const int tok  = tokens[base + lane];
    const bool bl  = (lane >= 53);

    // u in registers: U0 = dims 4*lane.., U1 = dims 44+4*lane (lanes>=53 only, else 0)
    const float4* u4 = (const float4*)(u_ws + (size_t)seg * DD);
    const float4 U0 = u4[lane];
    float4 U1 = make_float4(0.f, 0.f, 0.f, 0.f);
    if (bl) U1 = u4[11 + lane];

    float4 A0[4], B0[4], A1[4], B1[4];
    #pragma unroll
    for (int i = 0; i < 4; ++i) {
        B0[i] = make_float4(0.f, 0.f, 0.f, 0.f);
        B1[i] = make_float4(0.f, 0.f, 0.f, 0.f);
    }

    // ---- esc: chunk-8 pipelined; 4 independent reduce chains per half-chunk ----
    float esc = 0.f;
    const int len8 = (len + 7) & ~7;
    ld_rows(emb, tok, len, 0, lane, bl, A0, B0);
    for (int l0 = 0; l0 < len8; l0 += 8) {
        ld_rows(emb, tok, len, l0 + 4, lane, bl, A1, B1);
        {
            float d0 = dot4(A0[0], U0) + dot4(B0[0], U1);
            float d1 = dot4(A0[1], U0) + dot4(B0[1], U1);
            float d2 = dot4(A0[2], U0) + dot4(B0[2], U1);
            float d3 = dot4(A0[3], U0) + dot4(B0[3], U1);
            d0 = wave_sum(d0); d1 = wave_sum(d1); d2 = wave_sum(d2); d3 = wave_sum(d3);
            esc = (lane == l0 + 0) ? d0 : esc;
            esc = (lane == l0 + 1) ? d1 : esc;
            esc = (lane == l0 + 2) ? d2 : esc;
            esc = (lane == l0 + 3) ? d3 : esc;
        }
        ld_rows(emb, tok, len, l0 + 8, lane, bl, A0, B0);
        {
            float d0 = dot4(A1[0], U0) + dot4(B1[0], U1);
            float d1 = dot4(A1[1], U0) + dot4(B1[1], U1);
            float d2 = dot4(A1[2], U0) + dot4(B1[2], U1);
            float d3 = dot4(A1[3], U0) + dot4(B1[3], U1);
            d0 = wave_sum(d0); d1 = wave_sum(d1); d2 = wave_sum(d2); d3 = wave_sum(d3);
            esc = (lane == l0 + 4) ? d0 : esc;
            esc = (lane == l0 + 5) ? d1 : esc;
            esc = (lane == l0 + 6) ? d2 : esc;
            esc = (lane == l0 + 7) ? d3 : esc;
        }
    }

    // ---- softmax over rows, all in-wave (lane = row) ----
    const float v  = (lane < len) ? esc : -INFINITY;
    const float mx = wave_max(v);
    const float ex = (lane < len) ? __expf(v - mx) : 0.f;
    const float sm = wave_sum(ex);
    const float alpha = ex / sm;          // 0 for pad lanes

    // ---- z: re-read rows (L2-hot), alpha-weighted; alpha(l)=0 kills clamped pads ----
    float4 zA = make_float4(0.f, 0.f, 0.f, 0.f);
    float4 zB = make_float4(0.f, 0.f, 0.f, 0.f);
    ld_rows(emb, tok, len, 0, lane, bl, A0, B0);
    for (int l0 = 0; l0 < len8; l0 += 8) {
        ld_rows(emb, tok, len, l0 + 4, lane, bl, A1, B1);
        #pragma unroll
        for (int i = 0; i < 4; ++i) {
            const float a = __shfl(alpha, l0 + i);
            fma4(zA, a, A0[i]); fma4(zB, a, B0[i]);
        }
        ld_rows(emb, tok, len, l0 + 8, lane, bl, A0, B0);
        #pragma unroll
        for (int i = 0; i < 4; ++i) {
            const float a = __shfl(alpha, l0 + 4 + i);
            fma4(zA, a, A1[i]); fma4(zB, a, B1[i]);
        }
    }
    {
        float4* zo = (float4*)(out_z + (size_t)seg * DD);
        zo[lane] = zA;
        if (bl) zo[11 + lane] = zB;
    }

    // ---- p: 50 wave-dots vs register z, chunk-8 pipelined (k rows clamped to 49) ----
    float sc = 0.f;
    ld_wrows(W_w, KK - 1, DD, 0, lane, bl, A0, B0);
    for (int k0 = 0; k0 < 56; k0 += 8) {
        ld_wrows(W_w, KK - 1, DD, k0 + 4, lane, bl, A1, B1);
        {
            float t0 = dot4(A0[0], zA) + dot4(B0[0], zB);
            float t1 = dot4(A0[1], zA) + dot4(B0[1], zB);
            float t2 = dot4(A0[2], zA) + dot4(B0[2], zB);
            float t3 = dot4(A0[3], zA) + dot4(B0[3], zB);
            t0 = wave_sum(t0); t1 = wave_sum(t1); t2 = wave_sum(t2); t3 = wave_sum(t3);
            sc = (lane == k0 + 0) ? t0 : sc;
            sc = (lane == k0 + 1) ? t1 : sc;
            sc = (lane == k0 + 2) ? t2 : sc;
            sc = (lane == k0 + 3) ? t3 : sc;
        }
        ld_wrows(W_w, KK - 1, DD, k0 + 8, lane, bl, A0, B0);
        {
            float t0 = dot4(A1[0], zA) + dot4(B1[0], zB);
            float t1 = dot4(A1[1], zA) + dot4(B1[1], zB);
            float t2 = dot4(A1[2], zA) + dot4(B1[2], zB);
            float t3 = dot4(A1[3], zA) + dot4(B1[3], zB);
            t0 = wave_sum(t0); t1 = wave_sum(t1); t2 = wave_sum(t2); t3 = wave_sum(t3);
            sc = (lane == k0 + 4) ? t0 : sc;
            sc = (lane == k0 + 5) ? t1 : sc;
            sc = (lane == k0 + 6) ? t2 : sc;
            sc = (lane == k0 + 7) ? t3 : sc;
        }
    }
    const float vk  = (lane < KK) ? sc : -INFINITY;
    const float mxk = wave_max(vk);
    const float ek  = (lane < KK) ? __expf(vk - mxk) : 0.f;
    const float smk = wave_sum(ek);
    const float p   = ek / smk;           // 0 for lanes >= 50
    if (lane < KK) out_p[(size_t)seg * KK + lane] = p;

    // ---- r = p @ T_w.T ----
    float4 rA = make_float4(0.f, 0.f, 0.f, 0.f);
    float4 rB = make_float4(0.f, 0.f, 0.f, 0.f);
    if (use_tt) {
        // Tt rows 50..63 are zeros; p(k>=50)=0 — no clamping needed anywhere
        ld_wrows(Tt, TTR - 1, TTP, 0, lane, bl, A0, B0);
        for (int k0 = 0; k0 < 56; k0 += 8) {
            ld_wrows(Tt, TTR - 1, TTP, k0 + 4, lane, bl, A1, B1);
            #pragma unroll
            for (int i = 0; i < 4; ++i) {
                const float pk = __shfl(p, k0 + i);
                fma4(rA, pk, A0[i]); fma4(rB, pk, B0[i]);
            }
            ld_wrows(Tt, TTR - 1, TTP, k0 + 8, lane, bl, A0, B0);
            #pragma unroll
            for (int i = 0; i < 4; ++i) {
                const float pk = __shfl(p, k0 + 4 + i);
                fma4(rA, pk, A1[i]); fma4(rB, pk, B1[i]);
            }
        }
    } else {
        // fallback: scalar T_w reads (L1/L2-hot, 60KB)
        const int dA = 4 * lane, dB = 44 + 4 * lane;
        for (int k = 0; k < KK; ++k) {
            const float pk = __shfl(p, k);
            rA.x += pk * T_w[(size_t)(dA + 0) * KK + k];
            rA.y += pk * T_w[(size_t)(dA + 1) * KK + k];
            rA.z += pk * T_w[(size_t)(dA + 2) * KK + k];
            rA.w += pk * T_w[(size_t)(dA + 3) * KK + k];
            if (bl) {
                rB.x += pk * T_w[(size_t)(dB + 0) * KK + k];
                rB.y += pk * T_w[(size_t)(dB + 1) * KK + k];
                rB.z += pk * T_w[(size_t)(dB + 2) * KK + k];
                rB.w += pk * T_w[(size_t)(dB + 3) * KK + k];
            }
        }
    }
    {
        float4* ro = (float4*)(out_r + (size_t)seg * DD);
        ro[lane] = rA;
        if (bl) ro[11 + lane] = rB;
    }
}

extern "C" void kernel_launch(void* const* d_in, const int* in_sizes, int n_in,
                              void* d_out, int out_size, void* d_ws, size_t ws_size,
                              hipStream_t stream) {
    const float* emb        = (const float*)d_in[0];
    const float* M_w        = (const float*)d_in[1];
    const float* W_w        = (const float*)d_in[2];
    const float* T_w        = (const float*)d_in[3];
    const int*   tokens     = (const int*)d_in[4];
    const int*   seg_starts = (const int*)d_in[5];
    const int*   seg_lens   = (const int*)d_in[6];

    float* out   = (float*)d_out;
    float* out_y = out;
    float* out_z = out + (size_t)NSEG * DD;
    float* out_p = out + (size_t)2 * NSEG * DD;
    float* out_r = out + (size_t)2 * NSEG * DD + (size_t)NSEG * KK;

    float* u_ws = (float*)d_ws;                              // NSEG*DD floats
    float* Tt   = u_ws + (size_t)NSEG * DD;                  // TTR*TTP floats
    const size_t need = ((size_t)NSEG * DD + (size_t)TTR * TTP) * sizeof(float);
    const int use_tt = (ws_size >= need) ? 1 : 0;

    if (use_tt)
        hipLaunchKernelGGL(k_tt, dim3(TTR), dim3(TTP), 0, stream, T_w, Tt);
    hipLaunchKernelGGL(k_y1, dim3(NSEG / 4), dim3(256), 0, stream,
                       emb, tokens, seg_starts, seg_lens, out_y);
    hipLaunchKernelGGL(k_u, dim3(NSEG / TM), dim3(NTU), 0, stream,
                       out_y, M_w, u_ws);
    hipLaunchKernelGGL(k_rest, dim3(NSEG / 4), dim3(256), 0, stream,
                       emb, W_w, T_w, Tt, use_tt, tokens, seg_starts, seg_lens,
                       u_ws, out_z, out_p, out_r);
}